// Round 8
// baseline (88.998 us; speedup 1.0000x reference)
//
#include <hip/hip_runtime.h>

#define DI __device__ __forceinline__

typedef __bf16 bf16x8 __attribute__((ext_vector_type(8)));
typedef float  f32x4  __attribute__((ext_vector_type(4)));
typedef unsigned short u16;
typedef unsigned int   u32;

constexpr int BATCH  = 2;
constexpr int NNODE  = 4097;          // 64*64 grid + 1 global token
constexpr int M_REAL = BATCH * NNODE; // 8194
constexpr int M_PAD  = 8448;          // 33 * 256
constexpr int KDIM   = 512;

// dense global-token row: split-K softmax partials
constexpr int JC     = 256;                        // keys per chunk
constexpr int NCHUNK = (NNODE + JC - 1) / JC;      // 17
constexpr int NDB    = BATCH * 8 * NCHUNK;         // 272 dense phase-A blocks

DI float bf2f(u16 u)  { return __uint_as_float(((u32)u) << 16); }
DI float bflo(u32 v)  { return __uint_as_float(v << 16); }
DI float bfhi(u32 v)  { return __uint_as_float(v & 0xffff0000u); }
DI u16   f2bf(float f) {
  u32 u = __float_as_uint(f);
  u32 r = (u + 0x7fffu + ((u >> 16) & 1u)) >> 16;   // RNE
  return (u16)r;
}

DI void gload_lds16(const void* g, void* l) {
  __builtin_amdgcn_global_load_lds(
      (const __attribute__((address_space(1))) u32*)g,
      (__attribute__((address_space(3))) u32*)l, 16, 0, 0);
}

// ---------------------------------------------------------------- prep ----
constexpr int NCH_X  = M_PAD * KDIM / 8;   // 540672
constexpr int NCH_WQ = 1536 * KDIM / 8;    // 98304
constexpr int NCH_WO = 512 * KDIM / 8;     // 32768

__global__ __launch_bounds__(256) void prep(
    const float* __restrict__ x,  const float* __restrict__ wq,
    const float* __restrict__ wk, const float* __restrict__ wv,
    const float* __restrict__ wo,
    u16* __restrict__ Xp, u16* __restrict__ Wqkv, u16* __restrict__ Wob,
    u32* __restrict__ Cnt) {
  int idx = blockIdx.x * 256 + threadIdx.x;
  if (idx < 16) Cnt[idx] = 0;   // reset per-(b,h) merge counters every call
  const float* src = nullptr;
  u16* dst = nullptr;
  bool zero = false;
  if (idx < NCH_X) {
    int row = idx >> 6;
    dst = Xp + (size_t)idx * 8;
    if (row < M_REAL) src = x + (size_t)idx * 8; else zero = true;
  } else if (idx < NCH_X + NCH_WQ) {
    int t = idx - NCH_X;
    int row = t >> 6;
    dst = Wqkv + (size_t)t * 8;
    const float* W = row < 512 ? wq : (row < 1024 ? wk : wv);
    src = W + ((size_t)(row & 511) << 9) + ((t & 63) * 8);
  } else if (idx < NCH_X + NCH_WQ + NCH_WO) {
    int t = idx - NCH_X - NCH_WQ;
    dst = Wob + (size_t)t * 8;
    src = wo + (size_t)t * 8;
  } else {
    return;
  }
  u32 o[4];
  if (zero) {
    o[0] = o[1] = o[2] = o[3] = 0u;
  } else {
    float4 f0 = ((const float4*)src)[0];
    float4 f1 = ((const float4*)src)[1];
    o[0] = (u32)f2bf(f0.x) | ((u32)f2bf(f0.y) << 16);
    o[1] = (u32)f2bf(f0.z) | ((u32)f2bf(f0.w) << 16);
    o[2] = (u32)f2bf(f1.x) | ((u32)f2bf(f1.y) << 16);
    o[3] = (u32)f2bf(f1.z) | ((u32)f2bf(f1.w) << 16);
  }
  uint4 v; v.x = o[0]; v.y = o[1]; v.z = o[2]; v.w = o[3];
  *(uint4*)dst = v;
}

// ------------------------------------------------- 256x256 dbuf GEMM ------
// 1D grid 198, bijective XCD-chunked swizzle (q=24,r=6), y-major: each XCD
// works ~5 consecutive bx columns (A 1.3MB + B 1.5MB fits its 4MB L2).
__global__ __launch_bounds__(512, 2) void gemm256(
    const u16* __restrict__ A, const u16* __restrict__ B,
    u16* __restrict__ C) {
  __shared__ __align__(16) u16 SM[65536];
  const int tid  = threadIdx.x;
  const int lane = tid & 63;
  const int wid  = tid >> 6;
  const int wm   = wid >> 2;
  const int wn   = wid & 3;

  const int obid = blockIdx.x;            // 0..197
  const int xcd = obid & 7, loc = obid >> 3;
  const int wgid = (xcd < 6) ? xcd * 25 + loc : 150 + (xcd - 6) * 24 + loc;
  const int m0 = (wgid / 6) * 256;
  const int n0 = (wgid % 6) * 256;

  const int l15 = lane & 15, l7 = lane & 7, lg = lane >> 4;

  const int srow = tid >> 3;
  const int scol = ((tid & 7) ^ (srow & 7)) << 3;
  const u16* Ag = A + (size_t)(m0 + srow) * KDIM + scol;
  const u16* Bg = B + (size_t)(n0 + srow) * KDIM + scol;

  const int kx0 = ((lg * 8)        ^ (l7 << 3));
  const int kx1 = (((4 | lg) * 8)  ^ (l7 << 3));
  const int aBase = wm * 8192 + l15 * 64;
  const int bBase = 32768 + (wn >> 1) * 8192 + ((wn & 1) * 64 + l15) * 64;

  f32x4 acc[8][4] = {};

  constexpr int NT = KDIM / 64;

  auto stage = [&](int t, int buf) {
    const int ab = buf * 32768;
    const u16* ga = Ag + t * 64;
    const u16* gb = Bg + t * 64;
#pragma unroll
    for (int h = 0; h < 4; ++h) {
      gload_lds16(ga + (size_t)h * 64 * KDIM, (char*)SM + ab + h * 8192 + tid * 16);
      gload_lds16(gb + (size_t)h * 64 * KDIM, (char*)SM + 65536 + ab + h * 8192 + tid * 16);
    }
  };

  stage(0, 0);

  for (int t = 0; t < NT; ++t) {
    const int buf = t & 1;
    if (t + 1 < NT) {
      stage(t + 1, buf ^ 1);
      asm volatile("s_waitcnt vmcnt(8)" ::: "memory");
    } else {
      asm volatile("s_waitcnt vmcnt(0)" ::: "memory");
    }
    asm volatile("s_barrier" ::: "memory");

    const int aB = aBase + buf * 16384;
    const int bB = bBase + buf * 16384;

    bf16x8 bfr[4][2];
#pragma unroll
    for (int ni = 0; ni < 4; ++ni) {
      bfr[ni][0] = *(const bf16x8*)&SM[bB + ni * 1024 + kx0];
      bfr[ni][1] = *(const bf16x8*)&SM[bB + ni * 1024 + kx1];
    }
#pragma unroll
    for (int qm = 0; qm < 2; ++qm) {
      bf16x8 af[4][2];
#pragma unroll
      for (int i = 0; i < 4; ++i) {
        const int mi = qm * 4 + i;
        af[i][0] = *(const bf16x8*)&SM[aB + mi * 1024 + kx0];
        af[i][1] = *(const bf16x8*)&SM[aB + mi * 1024 + kx1];
      }
      __builtin_amdgcn_s_setprio(1);
#pragma unroll
      for (int i = 0; i < 4; ++i)
#pragma unroll
        for (int ni = 0; ni < 4; ++ni) {
          acc[qm*4+i][ni] = __builtin_amdgcn_mfma_f32_16x16x32_bf16(
              af[i][0], bfr[ni][0], acc[qm*4+i][ni], 0, 0, 0);
          acc[qm*4+i][ni] = __builtin_amdgcn_mfma_f32_16x16x32_bf16(
              af[i][1], bfr[ni][1], acc[qm*4+i][ni], 0, 0, 0);
        }
      __builtin_amdgcn_s_setprio(0);
    }
    asm volatile("s_barrier" ::: "memory");
  }

  const int cr = lg * 4, cc = l15;
#pragma unroll
  for (int mi = 0; mi < 8; ++mi)
#pragma unroll
    for (int j = 0; j < 4; ++j) {
      const int row = m0 + wm * 128 + mi * 16 + cr + j;
#pragma unroll
      for (int ni = 0; ni < 4; ++ni) {
        const int col = n0 + wn * 64 + ni * 16 + cc;
        C[(size_t)row * 1536 + col] = f2bf(acc[mi][ni][j]);
      }
    }
}

// ------------------------- 128x128 dbuf GEMM (swizzled, counted vmcnt) ----
// 1D grid 260, bijective XCD swizzle (q=32,r=4), y-major linearization.
template <int N, bool OUT_F32>
__global__ __launch_bounds__(256, 2) void gemm128(
    const u16* __restrict__ A, const u16* __restrict__ B,
    u16* __restrict__ Cb, float* __restrict__ Cf) {
  __shared__ __align__(16) u16 SM[32768];
  const int tid  = threadIdx.x;
  const int lane = tid & 63;
  const int wid  = tid >> 6;
  const int wm   = wid >> 1, wn = wid & 1;

  const int obid = blockIdx.x;            // 0..259
  const int xcd = obid & 7, loc = obid >> 3;
  const int wgid = (xcd < 4) ? xcd * 33 + loc : 132 + (xcd - 4) * 32 + loc;
  const int m0 = (wgid >> 2) * 128;
  const int n0 = (wgid & 3) * 128;

  const int l15 = lane & 15, l7 = lane & 7, lg = lane >> 4;

  const int srow = tid >> 3;
  const int scol = ((tid & 7) ^ (srow & 7)) << 3;
  const u16* Ag = A + (size_t)(m0 + srow) * KDIM + scol;
  const u16* Bg = B + (size_t)(n0 + srow) * KDIM + scol;

  const int kx0 = ((lg * 8)       ^ (l7 << 3));
  const int kx1 = (((4 | lg) * 8) ^ (l7 << 3));
  const int aBase = wm * 4096 + l15 * 64;
  const int bBase = 16384 + wn * 4096 + l15 * 64;

  f32x4 acc[4][4] = {};
  constexpr int NT = KDIM / 64;

  auto stage = [&](int t, int buf) {
    const int ab = buf * 16384;
    const u16* ga = Ag + t * 64;
    const u16* gb = Bg + t * 64;
#pragma unroll
    for (int h = 0; h < 4; ++h) {
      gload_lds16(ga + (size_t)h * 32 * KDIM, (char*)SM + ab + h * 4096 + tid * 16);
      gload_lds16(gb + (size_t)h * 32 * KDIM, (char*)SM + 32768 + ab + h * 4096 + tid * 16);
    }
  };

  stage(0, 0);

  for (int t = 0; t < NT; ++t) {
    const int buf = t & 1;
    if (t + 1 < NT) {
      stage(t + 1, buf ^ 1);
      asm volatile("s_waitcnt vmcnt(8)" ::: "memory");
    } else {
      asm volatile("s_waitcnt vmcnt(0)" ::: "memory");
    }
    asm volatile("s_barrier" ::: "memory");

    const int aB = aBase + buf * 8192;
    const int bB = bBase + buf * 8192;

    bf16x8 bfr[4][2];
#pragma unroll
    for (int ni = 0; ni < 4; ++ni) {
      bfr[ni][0] = *(const bf16x8*)&SM[bB + ni * 1024 + kx0];
      bfr[ni][1] = *(const bf16x8*)&SM[bB + ni * 1024 + kx1];
    }
    bf16x8 af[4][2];
#pragma unroll
    for (int i = 0; i < 4; ++i) {
      af[i][0] = *(const bf16x8*)&SM[aB + i * 1024 + kx0];
      af[i][1] = *(const bf16x8*)&SM[aB + i * 1024 + kx1];
    }
    __builtin_amdgcn_s_setprio(1);
#pragma unroll
    for (int i = 0; i < 4; ++i)
#pragma unroll
      for (int ni = 0; ni < 4; ++ni) {
        acc[i][ni] = __builtin_amdgcn_mfma_f32_16x16x32_bf16(
            af[i][0], bfr[ni][0], acc[i][ni], 0, 0, 0);
        acc[i][ni] = __builtin_amdgcn_mfma_f32_16x16x32_bf16(
            af[i][1], bfr[ni][1], acc[i][ni], 0, 0, 0);
      }
    __builtin_amdgcn_s_setprio(0);
    asm volatile("s_barrier" ::: "memory");
  }

  const int cr = lg * 4, cc = l15;
#pragma unroll
  for (int mi = 0; mi < 4; ++mi)
#pragma unroll
    for (int j = 0; j < 4; ++j) {
      const int row = m0 + wm * 64 + mi * 16 + cr + j;
      if (OUT_F32 && row >= M_REAL) continue;
#pragma unroll
      for (int ni = 0; ni < 4; ++ni) {
        const int col = n0 + wn * 64 + ni * 16 + cc;
        if constexpr (OUT_F32)
          Cf[(size_t)row * N + col] = acc[mi][ni][j];
        else
          Cb[(size_t)row * N + col] = f2bf(acc[mi][ni][j]);
      }
    }
}

// ------------------------------------------------------------ attention ----
// blocks [0,NDB): dense-row phase A; the LAST finisher per (b,h) (16
// per-(b,h) atomic counters, zeroed by prep) merges that row's 17 partials
// in parallel with the other 15 — no serial tail, no attn_fin launch.
// blocks [NDB,..): sparse rows, one wave per (b, node), XCD-chunked swizzle.
__global__ __launch_bounds__(256) void attn(const u16* __restrict__ QKV,
                                            u16* __restrict__ O,
                                            float* __restrict__ Part,
                                            u32* __restrict__ Cnt) {
  const int tid = threadIdx.x;
  if (blockIdx.x < NDB) {
    __shared__ float qs[64];
    __shared__ float ev[JC];
    __shared__ float red[256];
    __shared__ float pm[NCHUNK * 66];
    __shared__ int winner;
    const int db = blockIdx.x;
    const int b  = db / (8 * NCHUNK);
    const int rm = db % (8 * NCHUNK);
    const int h  = rm / NCHUNK;
    const int ch = rm % NCHUNK;
    const int j0 = ch * JC;
    const size_t base = (size_t)b * NNODE;

    if (tid < 64) qs[tid] = bf2f(QKV[base * 1536 + h * 64 + tid]);
    __syncthreads();

    const int j = j0 + tid;
    float s = -3e38f;
    if (j < NNODE) {
      const uint4* kp4 = (const uint4*)(QKV + (base + j) * 1536 + 512 + h * 64);
      float a = 0.f;
#pragma unroll
      for (int q8 = 0; q8 < 8; ++q8) {
        uint4 kv = kp4[q8];
        int d = q8 * 8;
        a += qs[d+0]*bflo(kv.x) + qs[d+1]*bfhi(kv.x)
           + qs[d+2]*bflo(kv.y) + qs[d+3]*bfhi(kv.y)
           + qs[d+4]*bflo(kv.z) + qs[d+5]*bfhi(kv.z)
           + qs[d+6]*bflo(kv.w) + qs[d+7]*bfhi(kv.w);
      }
      s = a * 0.125f;
    }
    red[tid] = s;
    __syncthreads();
    for (int st = 128; st > 0; st >>= 1) {
      if (tid < st) red[tid] = fmaxf(red[tid], red[tid + st]);
      __syncthreads();
    }
    const float mx = red[0];
    __syncthreads();
    const float e = (j < NNODE) ? __expf(s - mx) : 0.f;
    ev[tid] = e;
    red[tid] = e;
    __syncthreads();
    for (int st = 128; st > 0; st >>= 1) {
      if (tid < st) red[tid] += red[tid + st];
      __syncthreads();
    }
    const float ssum = red[0];
    __syncthreads();

    const int w = tid >> 6, lane = tid & 63;
    const int js = lane >> 3, dg = lane & 7;
    float oa[8] = {};
#pragma unroll
    for (int jj = 0; jj < 8; ++jj) {
      const int li = w * 64 + jj * 8 + js;
      const int jv = j0 + li;
      if (jv < NNODE) {
        const float we = ev[li];
        const uint4 vv = *(const uint4*)(QKV + (base + jv) * 1536 + 1024 + h * 64 + dg * 8);
        oa[0] += we * bflo(vv.x); oa[1] += we * bfhi(vv.x);
        oa[2] += we * bflo(vv.y); oa[3] += we * bfhi(vv.y);
        oa[4] += we * bflo(vv.z); oa[5] += we * bfhi(vv.z);
        oa[6] += we * bflo(vv.w); oa[7] += we * bfhi(vv.w);
      }
    }
#pragma unroll
    for (int m = 8; m <= 32; m <<= 1)
#pragma unroll
      for (int t = 0; t < 8; ++t) oa[t] += __shfl_xor(oa[t], m);
    __syncthreads();
    if (lane < 8) {
#pragma unroll
      for (int t = 0; t < 8; ++t) red[w * 64 + lane * 8 + t] = oa[t];
    }
    __syncthreads();
    float* P = Part + ((size_t)((b * 8 + h) * NCHUNK + ch)) * 66;
    if (tid == 0) { P[0] = mx; P[1] = ssum; }
    if (tid < 64)
      P[2 + tid] = red[tid] + red[64 + tid] + red[128 + tid] + red[192 + tid];

    // ---- per-(b,h) election: last finisher merges (release/acquire) ----
    __threadfence();
    if (tid == 0)
      winner = (atomicAdd(&Cnt[b * 8 + h], 1u) == (u32)(NCHUNK - 1)) ? 1 : 0;
    __syncthreads();
    if (!winner) return;
    __threadfence();
    const float* Pbh = Part + (size_t)(b * 8 + h) * NCHUNK * 66;
    for (int t2 = tid; t2 < NCHUNK * 66; t2 += 256) pm[t2] = Pbh[t2];
    __syncthreads();
    if (tid < 64) {
      float m = -3e38f;
#pragma unroll
      for (int c2 = 0; c2 < NCHUNK; ++c2) m = fmaxf(m, pm[c2 * 66]);
      float ssm = 0.f, o = 0.f;
#pragma unroll
      for (int c2 = 0; c2 < NCHUNK; ++c2) {
        const float ex = __expf(pm[c2 * 66] - m);
        ssm += pm[c2 * 66 + 1] * ex;
        o   += pm[c2 * 66 + 2 + tid] * ex;
      }
      O[base * 512 + h * 64 + tid] = f2bf(o / ssm);
    }
    return;
  }

  // ---- sparse rows ----
  const int obid = blockIdx.x - NDB;                    // 0..2047
  const int sb   = ((obid & 7) << 8) | (obid >> 3);     // bijective (2048 % 8 == 0)
  const int wid  = sb * 4 + (tid >> 6);                 // 0..8191
  const int lane = tid & 63;
  const int b = wid >> 12;
  const int g = wid & 4095;
  const int i = g + 1;
  const int r = g >> 6, c = g & 63;
  const size_t base = (size_t)b * NNODE;

  int  jn[6];
  bool vd[6];
  jn[0] = 0;                     vd[0] = true;
  jn[1] = i;                     vd[1] = true;
  jn[2] = (c > 0)  ? i - 1  : i; vd[2] = (c > 0);
  jn[3] = (c < 63) ? i + 1  : i; vd[3] = (c < 63);
  jn[4] = (r > 0)  ? i - 64 : i; vd[4] = (r > 0);
  jn[5] = (r < 63) ? i + 64 : i; vd[5] = (r < 63);

  const uint4 qv = *(const uint4*)(QKV + (base + i) * 1536 + lane * 8);
  float qf[8] = { bflo(qv.x), bfhi(qv.x), bflo(qv.y), bfhi(qv.y),
                  bflo(qv.z), bfhi(qv.z), bflo(qv.w), bfhi(qv.w) };

  float sc[6];
#pragma unroll
  for (int n = 0; n < 6; ++n) {
    const uint4 kv = *(const uint4*)(QKV + (base + jn[n]) * 1536 + 512 + lane * 8);
    float p = qf[0]*bflo(kv.x) + qf[1]*bfhi(kv.x)
            + qf[2]*bflo(kv.y) + qf[3]*bfhi(kv.y)
            + qf[4]*bflo(kv.z) + qf[5]*bfhi(kv.z)
            + qf[6]*bflo(kv.w) + qf[7]*bfhi(kv.w);
    p += __shfl_xor(p, 1);
    p += __shfl_xor(p, 2);
    p += __shfl_xor(p, 4);
    sc[n] = p * 0.125f;
  }
  float mx = -1e30f;
#pragma unroll
  for (int n = 0; n < 6; ++n) if (vd[n]) mx = fmaxf(mx, sc[n]);
  float pw[6], den = 0.f;
#pragma unroll
  for (int n = 0; n < 6; ++n) {
    pw[n] = vd[n] ? __expf(sc[n] - mx) : 0.f;
    den += pw[n];
  }
  const float inv = 1.f / den;

  float oa[8] = {};
#pragma unroll
  for (int n = 0; n < 6; ++n) {
    const uint4 vv = *(const uint4*)(QKV + (base + jn[n]) * 1536 + 1024 + lane * 8);
    const float w = pw[n];
    oa[0] += w * bflo(vv.x); oa[1] += w * bfhi(vv.x);
    oa[2] += w * bflo(vv.y); oa[3] += w * bfhi(vv.y);
    oa[4] += w * bflo(vv.z); oa[5] += w * bfhi(vv.z);
    oa[6] += w * bflo(vv.w); oa[7] += w * bfhi(vv.w);
  }
  uint4 ov;
  ov.x = (u32)f2bf(oa[0] * inv) | ((u32)f2bf(oa[1] * inv) << 16);
  ov.y = (u32)f2bf(oa[2] * inv) | ((u32)f2bf(oa[3] * inv) << 16);
  ov.z = (u32)f2bf(oa[4] * inv) | ((u32)f2bf(oa[5] * inv) << 16);
  ov.w = (u32)f2bf(oa[6] * inv) | ((u32)f2bf(oa[7] * inv) << 16);
  *(uint4*)(O + (base + i) * 512 + lane * 8) = ov;
}

// -------------------------------------------------------------- launch ----
extern "C" void kernel_launch(void* const* d_in, const int* in_sizes, int n_in,
                              void* d_out, int out_size, void* d_ws, size_t ws_size,
                              hipStream_t stream) {
  (void)in_sizes; (void)n_in; (void)out_size; (void)ws_size;
  const float* x  = (const float*)d_in[0];
  const float* wq = (const float*)d_in[1];
  const float* wk = (const float*)d_in[2];
  const float* wv = (const float*)d_in[3];
  const float* wo = (const float*)d_in[4];
  float* out = (float*)d_out;

  char* ws = (char*)d_ws;
  u16* Xp   = (u16*)ws;  ws += (size_t)M_PAD * 512 * 2;   //  8,650,752 B
  u16* Wqkv = (u16*)ws;  ws += (size_t)1536 * 512 * 2;    //  1,572,864 B
  u16* Wob  = (u16*)ws;  ws += (size_t)512 * 512 * 2;     //    524,288 B
  u16* QKV  = (u16*)ws;  ws += (size_t)M_PAD * 1536 * 2;  // 25,952,256 B
  u16* ATT  = (u16*)ws;                                   //  8,650,752 B
  float* Part = (float*)Xp;  // dead after gemm1; 272*66*4 = 72 KB
  // 16 merge counters parked in ATT rows >= 8320 (never written/read elsewhere)
  u32* Cnt = (u32*)(ATT + (size_t)8320 * 512);

  prep<<<(NCH_X + NCH_WQ + NCH_WO) / 256, 256, 0, stream>>>(
      x, wq, wk, wv, wo, Xp, Wqkv, Wob, Cnt);

  gemm256<<<198, 512, 0, stream>>>(Xp, Wqkv, QKV);

  attn<<<NDB + 2048, 256, 0, stream>>>(QKV, ATT, Part, Cnt);

  gemm128<512, true><<<260, 256, 0, stream>>>(ATT, Wob, nullptr, out);
}

// Round 9
// 59.150 us; speedup vs baseline: 1.5046x; 1.5046x over previous
//
#include <hip/hip_runtime.h>

#define DI __device__ __forceinline__

typedef __bf16 bf16x8 __attribute__((ext_vector_type(8)));
typedef float  f32x4  __attribute__((ext_vector_type(4)));
typedef unsigned short u16;
typedef unsigned int   u32;

constexpr int BATCH  = 2;
constexpr int NNODE  = 4097;          // 64*64 grid + 1 global token
constexpr int M_REAL = BATCH * NNODE; // 8194
constexpr int M_PAD  = 8448;          // 33 * 256
constexpr int KDIM   = 512;

// dense global-token row: split-K softmax partials
constexpr int JC     = 256;                        // keys per chunk
constexpr int NCHUNK = (NNODE + JC - 1) / JC;      // 17
constexpr int NDB    = BATCH * 8 * NCHUNK;         // 272 dense phase-A blocks

DI float bf2f(u16 u)  { return __uint_as_float(((u32)u) << 16); }
DI float bflo(u32 v)  { return __uint_as_float(v << 16); }
DI float bfhi(u32 v)  { return __uint_as_float(v & 0xffff0000u); }
DI u16   f2bf(float f) {
  u32 u = __float_as_uint(f);
  u32 r = (u + 0x7fffu + ((u >> 16) & 1u)) >> 16;   // RNE
  return (u16)r;
}

DI void gload_lds16(const void* g, void* l) {
  __builtin_amdgcn_global_load_lds(
      (const __attribute__((address_space(1))) u32*)g,
      (__attribute__((address_space(3))) u32*)l, 16, 0, 0);
}

// ---------------------------------------------------------------- prep ----
constexpr int NCH_X  = M_PAD * KDIM / 8;   // 540672
constexpr int NCH_WQ = 1536 * KDIM / 8;    // 98304
constexpr int NCH_WO = 512 * KDIM / 8;     // 32768

__global__ __launch_bounds__(256) void prep(
    const float* __restrict__ x,  const float* __restrict__ wq,
    const float* __restrict__ wk, const float* __restrict__ wv,
    const float* __restrict__ wo,
    u16* __restrict__ Xp, u16* __restrict__ Wqkv, u16* __restrict__ Wob) {
  int idx = blockIdx.x * 256 + threadIdx.x;
  const float* src = nullptr;
  u16* dst = nullptr;
  bool zero = false;
  if (idx < NCH_X) {
    int row = idx >> 6;
    dst = Xp + (size_t)idx * 8;
    if (row < M_REAL) src = x + (size_t)idx * 8; else zero = true;
  } else if (idx < NCH_X + NCH_WQ) {
    int t = idx - NCH_X;
    int row = t >> 6;
    dst = Wqkv + (size_t)t * 8;
    const float* W = row < 512 ? wq : (row < 1024 ? wk : wv);
    src = W + ((size_t)(row & 511) << 9) + ((t & 63) * 8);
  } else if (idx < NCH_X + NCH_WQ + NCH_WO) {
    int t = idx - NCH_X - NCH_WQ;
    dst = Wob + (size_t)t * 8;
    src = wo + (size_t)t * 8;
  } else {
    return;
  }
  u32 o[4];
  if (zero) {
    o[0] = o[1] = o[2] = o[3] = 0u;
  } else {
    float4 f0 = ((const float4*)src)[0];
    float4 f1 = ((const float4*)src)[1];
    o[0] = (u32)f2bf(f0.x) | ((u32)f2bf(f0.y) << 16);
    o[1] = (u32)f2bf(f0.z) | ((u32)f2bf(f0.w) << 16);
    o[2] = (u32)f2bf(f1.x) | ((u32)f2bf(f1.y) << 16);
    o[3] = (u32)f2bf(f1.z) | ((u32)f2bf(f1.w) << 16);
  }
  uint4 v; v.x = o[0]; v.y = o[1]; v.z = o[2]; v.w = o[3];
  *(uint4*)dst = v;
}

// ------------------------------------------------- 256x256 dbuf GEMM ------
// 1D grid 198, bijective XCD-chunked swizzle (q=24,r=6), y-major: each XCD
// works ~4 consecutive bx rows of tiles (A-band + full B fit its 4MB L2).
__global__ __launch_bounds__(512, 2) void gemm256(
    const u16* __restrict__ A, const u16* __restrict__ B,
    u16* __restrict__ C) {
  __shared__ __align__(16) u16 SM[65536];
  const int tid  = threadIdx.x;
  const int lane = tid & 63;
  const int wid  = tid >> 6;
  const int wm   = wid >> 2;
  const int wn   = wid & 3;

  const int obid = blockIdx.x;            // 0..197
  const int xcd = obid & 7, loc = obid >> 3;
  const int wgid = (xcd < 6) ? xcd * 25 + loc : 150 + (xcd - 6) * 24 + loc;
  const int m0 = (wgid / 6) * 256;
  const int n0 = (wgid % 6) * 256;

  const int l15 = lane & 15, l7 = lane & 7, lg = lane >> 4;

  const int srow = tid >> 3;
  const int scol = ((tid & 7) ^ (srow & 7)) << 3;
  const u16* Ag = A + (size_t)(m0 + srow) * KDIM + scol;
  const u16* Bg = B + (size_t)(n0 + srow) * KDIM + scol;

  const int kx0 = ((lg * 8)        ^ (l7 << 3));
  const int kx1 = (((4 | lg) * 8)  ^ (l7 << 3));
  const int aBase = wm * 8192 + l15 * 64;
  const int bBase = 32768 + (wn >> 1) * 8192 + ((wn & 1) * 64 + l15) * 64;

  f32x4 acc[8][4] = {};

  constexpr int NT = KDIM / 64;

  auto stage = [&](int t, int buf) {
    const int ab = buf * 32768;
    const u16* ga = Ag + t * 64;
    const u16* gb = Bg + t * 64;
#pragma unroll
    for (int h = 0; h < 4; ++h) {
      gload_lds16(ga + (size_t)h * 64 * KDIM, (char*)SM + ab + h * 8192 + tid * 16);
      gload_lds16(gb + (size_t)h * 64 * KDIM, (char*)SM + 65536 + ab + h * 8192 + tid * 16);
    }
  };

  stage(0, 0);

  for (int t = 0; t < NT; ++t) {
    const int buf = t & 1;
    if (t + 1 < NT) {
      stage(t + 1, buf ^ 1);
      asm volatile("s_waitcnt vmcnt(8)" ::: "memory");
    } else {
      asm volatile("s_waitcnt vmcnt(0)" ::: "memory");
    }
    asm volatile("s_barrier" ::: "memory");

    const int aB = aBase + buf * 16384;
    const int bB = bBase + buf * 16384;

    bf16x8 bfr[4][2];
#pragma unroll
    for (int ni = 0; ni < 4; ++ni) {
      bfr[ni][0] = *(const bf16x8*)&SM[bB + ni * 1024 + kx0];
      bfr[ni][1] = *(const bf16x8*)&SM[bB + ni * 1024 + kx1];
    }
#pragma unroll
    for (int qm = 0; qm < 2; ++qm) {
      bf16x8 af[4][2];
#pragma unroll
      for (int i = 0; i < 4; ++i) {
        const int mi = qm * 4 + i;
        af[i][0] = *(const bf16x8*)&SM[aB + mi * 1024 + kx0];
        af[i][1] = *(const bf16x8*)&SM[aB + mi * 1024 + kx1];
      }
      __builtin_amdgcn_s_setprio(1);
#pragma unroll
      for (int i = 0; i < 4; ++i)
#pragma unroll
        for (int ni = 0; ni < 4; ++ni) {
          acc[qm*4+i][ni] = __builtin_amdgcn_mfma_f32_16x16x32_bf16(
              af[i][0], bfr[ni][0], acc[qm*4+i][ni], 0, 0, 0);
          acc[qm*4+i][ni] = __builtin_amdgcn_mfma_f32_16x16x32_bf16(
              af[i][1], bfr[ni][1], acc[qm*4+i][ni], 0, 0, 0);
        }
      __builtin_amdgcn_s_setprio(0);
    }
    asm volatile("s_barrier" ::: "memory");
  }

  const int cr = lg * 4, cc = l15;
#pragma unroll
  for (int mi = 0; mi < 8; ++mi)
#pragma unroll
    for (int j = 0; j < 4; ++j) {
      const int row = m0 + wm * 128 + mi * 16 + cr + j;
#pragma unroll
      for (int ni = 0; ni < 4; ++ni) {
        const int col = n0 + wn * 64 + ni * 16 + cc;
        C[(size_t)row * 1536 + col] = f2bf(acc[mi][ni][j]);
      }
    }
}

// ------------------------- 128x128 dbuf GEMM (swizzled, counted vmcnt) ----
// 1D grid 260, bijective XCD swizzle (q=32,r=4), y-major linearization.
template <int N, bool OUT_F32>
__global__ __launch_bounds__(256, 2) void gemm128(
    const u16* __restrict__ A, const u16* __restrict__ B,
    u16* __restrict__ Cb, float* __restrict__ Cf) {
  __shared__ __align__(16) u16 SM[32768];
  const int tid  = threadIdx.x;
  const int lane = tid & 63;
  const int wid  = tid >> 6;
  const int wm   = wid >> 1, wn = wid & 1;

  const int obid = blockIdx.x;            // 0..259
  const int xcd = obid & 7, loc = obid >> 3;
  const int wgid = (xcd < 4) ? xcd * 33 + loc : 132 + (xcd - 4) * 32 + loc;
  const int m0 = (wgid >> 2) * 128;
  const int n0 = (wgid & 3) * 128;

  const int l15 = lane & 15, l7 = lane & 7, lg = lane >> 4;

  const int srow = tid >> 3;
  const int scol = ((tid & 7) ^ (srow & 7)) << 3;
  const u16* Ag = A + (size_t)(m0 + srow) * KDIM + scol;
  const u16* Bg = B + (size_t)(n0 + srow) * KDIM + scol;

  const int kx0 = ((lg * 8)       ^ (l7 << 3));
  const int kx1 = (((4 | lg) * 8) ^ (l7 << 3));
  const int aBase = wm * 4096 + l15 * 64;
  const int bBase = 16384 + wn * 4096 + l15 * 64;

  f32x4 acc[4][4] = {};
  constexpr int NT = KDIM / 64;

  auto stage = [&](int t, int buf) {
    const int ab = buf * 16384;
    const u16* ga = Ag + t * 64;
    const u16* gb = Bg + t * 64;
#pragma unroll
    for (int h = 0; h < 4; ++h) {
      gload_lds16(ga + (size_t)h * 32 * KDIM, (char*)SM + ab + h * 4096 + tid * 16);
      gload_lds16(gb + (size_t)h * 32 * KDIM, (char*)SM + 32768 + ab + h * 4096 + tid * 16);
    }
  };

  stage(0, 0);

  for (int t = 0; t < NT; ++t) {
    const int buf = t & 1;
    if (t + 1 < NT) {
      stage(t + 1, buf ^ 1);
      asm volatile("s_waitcnt vmcnt(8)" ::: "memory");
    } else {
      asm volatile("s_waitcnt vmcnt(0)" ::: "memory");
    }
    asm volatile("s_barrier" ::: "memory");

    const int aB = aBase + buf * 8192;
    const int bB = bBase + buf * 8192;

    bf16x8 bfr[4][2];
#pragma unroll
    for (int ni = 0; ni < 4; ++ni) {
      bfr[ni][0] = *(const bf16x8*)&SM[bB + ni * 1024 + kx0];
      bfr[ni][1] = *(const bf16x8*)&SM[bB + ni * 1024 + kx1];
    }
    bf16x8 af[4][2];
#pragma unroll
    for (int i = 0; i < 4; ++i) {
      af[i][0] = *(const bf16x8*)&SM[aB + i * 1024 + kx0];
      af[i][1] = *(const bf16x8*)&SM[aB + i * 1024 + kx1];
    }
    __builtin_amdgcn_s_setprio(1);
#pragma unroll
    for (int i = 0; i < 4; ++i)
#pragma unroll
      for (int ni = 0; ni < 4; ++ni) {
        acc[i][ni] = __builtin_amdgcn_mfma_f32_16x16x32_bf16(
            af[i][0], bfr[ni][0], acc[i][ni], 0, 0, 0);
        acc[i][ni] = __builtin_amdgcn_mfma_f32_16x16x32_bf16(
            af[i][1], bfr[ni][1], acc[i][ni], 0, 0, 0);
      }
    __builtin_amdgcn_s_setprio(0);
    asm volatile("s_barrier" ::: "memory");
  }

  const int cr = lg * 4, cc = l15;
#pragma unroll
  for (int mi = 0; mi < 4; ++mi)
#pragma unroll
    for (int j = 0; j < 4; ++j) {
      const int row = m0 + wm * 64 + mi * 16 + cr + j;
      if (OUT_F32 && row >= M_REAL) continue;
#pragma unroll
      for (int ni = 0; ni < 4; ++ni) {
        const int col = n0 + wn * 64 + ni * 16 + cc;
        if constexpr (OUT_F32)
          Cf[(size_t)row * N + col] = acc[mi][ni][j];
        else
          Cb[(size_t)row * N + col] = f2bf(acc[mi][ni][j]);
      }
    }
}

// ------------------------------------------------------------ attention ----
// blocks [0,NDB): dense-row phase A (split-K partials -> Part)
// blocks [NDB,..): sparse rows, one wave per (b, node), XCD-chunked swizzle.
// NO intra-kernel merge election: R6/R8 both showed the fence/atomic election
// costs 23-33 us chip-wide; the separate 16-block attn_fin costs ~2 us.
__global__ __launch_bounds__(256) void attn(const u16* __restrict__ QKV,
                                            u16* __restrict__ O,
                                            float* __restrict__ Part) {
  const int tid = threadIdx.x;
  if (blockIdx.x < NDB) {
    __shared__ float qs[64];
    __shared__ float ev[JC];
    __shared__ float red[256];
    const int db = blockIdx.x;
    const int b  = db / (8 * NCHUNK);
    const int rm = db % (8 * NCHUNK);
    const int h  = rm / NCHUNK;
    const int ch = rm % NCHUNK;
    const int j0 = ch * JC;
    const size_t base = (size_t)b * NNODE;

    if (tid < 64) qs[tid] = bf2f(QKV[base * 1536 + h * 64 + tid]);
    __syncthreads();

    const int j = j0 + tid;
    float s = -3e38f;
    if (j < NNODE) {
      const uint4* kp4 = (const uint4*)(QKV + (base + j) * 1536 + 512 + h * 64);
      float a = 0.f;
#pragma unroll
      for (int q8 = 0; q8 < 8; ++q8) {
        uint4 kv = kp4[q8];
        int d = q8 * 8;
        a += qs[d+0]*bflo(kv.x) + qs[d+1]*bfhi(kv.x)
           + qs[d+2]*bflo(kv.y) + qs[d+3]*bfhi(kv.y)
           + qs[d+4]*bflo(kv.z) + qs[d+5]*bfhi(kv.z)
           + qs[d+6]*bflo(kv.w) + qs[d+7]*bfhi(kv.w);
      }
      s = a * 0.125f;
    }
    red[tid] = s;
    __syncthreads();
    for (int st = 128; st > 0; st >>= 1) {
      if (tid < st) red[tid] = fmaxf(red[tid], red[tid + st]);
      __syncthreads();
    }
    const float mx = red[0];
    __syncthreads();
    const float e = (j < NNODE) ? __expf(s - mx) : 0.f;
    ev[tid] = e;
    red[tid] = e;
    __syncthreads();
    for (int st = 128; st > 0; st >>= 1) {
      if (tid < st) red[tid] += red[tid + st];
      __syncthreads();
    }
    const float ssum = red[0];
    __syncthreads();

    const int w = tid >> 6, lane = tid & 63;
    const int js = lane >> 3, dg = lane & 7;
    float oa[8] = {};
#pragma unroll
    for (int jj = 0; jj < 8; ++jj) {
      const int li = w * 64 + jj * 8 + js;
      const int jv = j0 + li;
      if (jv < NNODE) {
        const float we = ev[li];
        const uint4 vv = *(const uint4*)(QKV + (base + jv) * 1536 + 1024 + h * 64 + dg * 8);
        oa[0] += we * bflo(vv.x); oa[1] += we * bfhi(vv.x);
        oa[2] += we * bflo(vv.y); oa[3] += we * bfhi(vv.y);
        oa[4] += we * bflo(vv.z); oa[5] += we * bfhi(vv.z);
        oa[6] += we * bflo(vv.w); oa[7] += we * bfhi(vv.w);
      }
    }
#pragma unroll
    for (int m = 8; m <= 32; m <<= 1)
#pragma unroll
      for (int t = 0; t < 8; ++t) oa[t] += __shfl_xor(oa[t], m);
    __syncthreads();
    if (lane < 8) {
#pragma unroll
      for (int t = 0; t < 8; ++t) red[w * 64 + lane * 8 + t] = oa[t];
    }
    __syncthreads();
    float* P = Part + ((size_t)((b * 8 + h) * NCHUNK + ch)) * 66;
    if (tid == 0) { P[0] = mx; P[1] = ssum; }
    if (tid < 64)
      P[2 + tid] = red[tid] + red[64 + tid] + red[128 + tid] + red[192 + tid];
    return;
  }

  // ---- sparse rows ----
  const int obid = blockIdx.x - NDB;                    // 0..2047
  const int sb   = ((obid & 7) << 8) | (obid >> 3);     // bijective (2048 % 8 == 0)
  const int wid  = sb * 4 + (tid >> 6);                 // 0..8191
  const int lane = tid & 63;
  const int b = wid >> 12;
  const int g = wid & 4095;
  const int i = g + 1;
  const int r = g >> 6, c = g & 63;
  const size_t base = (size_t)b * NNODE;

  int  jn[6];
  bool vd[6];
  jn[0] = 0;                     vd[0] = true;
  jn[1] = i;                     vd[1] = true;
  jn[2] = (c > 0)  ? i - 1  : i; vd[2] = (c > 0);
  jn[3] = (c < 63) ? i + 1  : i; vd[3] = (c < 63);
  jn[4] = (r > 0)  ? i - 64 : i; vd[4] = (r > 0);
  jn[5] = (r < 63) ? i + 64 : i; vd[5] = (r < 63);

  const uint4 qv = *(const uint4*)(QKV + (base + i) * 1536 + lane * 8);
  float qf[8] = { bflo(qv.x), bfhi(qv.x), bflo(qv.y), bfhi(qv.y),
                  bflo(qv.z), bfhi(qv.z), bflo(qv.w), bfhi(qv.w) };

  float sc[6];
#pragma unroll
  for (int n = 0; n < 6; ++n) {
    const uint4 kv = *(const uint4*)(QKV + (base + jn[n]) * 1536 + 512 + lane * 8);
    float p = qf[0]*bflo(kv.x) + qf[1]*bfhi(kv.x)
            + qf[2]*bflo(kv.y) + qf[3]*bfhi(kv.y)
            + qf[4]*bflo(kv.z) + qf[5]*bfhi(kv.z)
            + qf[6]*bflo(kv.w) + qf[7]*bfhi(kv.w);
    p += __shfl_xor(p, 1);
    p += __shfl_xor(p, 2);
    p += __shfl_xor(p, 4);
    sc[n] = p * 0.125f;
  }
  float mx = -1e30f;
#pragma unroll
  for (int n = 0; n < 6; ++n) if (vd[n]) mx = fmaxf(mx, sc[n]);
  float pw[6], den = 0.f;
#pragma unroll
  for (int n = 0; n < 6; ++n) {
    pw[n] = vd[n] ? __expf(sc[n] - mx) : 0.f;
    den += pw[n];
  }
  const float inv = 1.f / den;

  float oa[8] = {};
#pragma unroll
  for (int n = 0; n < 6; ++n) {
    const uint4 vv = *(const uint4*)(QKV + (base + jn[n]) * 1536 + 1024 + lane * 8);
    const float w = pw[n];
    oa[0] += w * bflo(vv.x); oa[1] += w * bfhi(vv.x);
    oa[2] += w * bflo(vv.y); oa[3] += w * bfhi(vv.y);
    oa[4] += w * bflo(vv.z); oa[5] += w * bfhi(vv.z);
    oa[6] += w * bflo(vv.w); oa[7] += w * bfhi(vv.w);
  }
  uint4 ov;
  ov.x = (u32)f2bf(oa[0] * inv) | ((u32)f2bf(oa[1] * inv) << 16);
  ov.y = (u32)f2bf(oa[2] * inv) | ((u32)f2bf(oa[3] * inv) << 16);
  ov.z = (u32)f2bf(oa[4] * inv) | ((u32)f2bf(oa[5] * inv) << 16);
  ov.w = (u32)f2bf(oa[6] * inv) | ((u32)f2bf(oa[7] * inv) << 16);
  *(uint4*)(O + (base + i) * 512 + lane * 8) = ov;
}

// phase B: merge the NCHUNK partials per (b,h), write O row 0 (16 parallel blocks).
__global__ __launch_bounds__(64) void attn_fin(const float* __restrict__ Part,
                                               u16* __restrict__ O) {
  const int b = blockIdx.x >> 3, h = blockIdx.x & 7;
  const int d = threadIdx.x;
  const float* P = Part + ((size_t)(b * 8 + h) * NCHUNK) * 66;
  float m = -3e38f;
  for (int c = 0; c < NCHUNK; ++c) m = fmaxf(m, P[c * 66]);
  float s = 0.f, o = 0.f;
  for (int c = 0; c < NCHUNK; ++c) {
    const float ex = __expf(P[c * 66] - m);
    s += P[c * 66 + 1] * ex;
    o += P[c * 66 + 2 + d] * ex;
  }
  O[(size_t)b * NNODE * 512 + h * 64 + d] = f2bf(o / s);
}

// -------------------------------------------------------------- launch ----
extern "C" void kernel_launch(void* const* d_in, const int* in_sizes, int n_in,
                              void* d_out, int out_size, void* d_ws, size_t ws_size,
                              hipStream_t stream) {
  (void)in_sizes; (void)n_in; (void)out_size; (void)ws_size;
  const float* x  = (const float*)d_in[0];
  const float* wq = (const float*)d_in[1];
  const float* wk = (const float*)d_in[2];
  const float* wv = (const float*)d_in[3];
  const float* wo = (const float*)d_in[4];
  float* out = (float*)d_out;

  char* ws = (char*)d_ws;
  u16* Xp   = (u16*)ws;  ws += (size_t)M_PAD * 512 * 2;   //  8,650,752 B
  u16* Wqkv = (u16*)ws;  ws += (size_t)1536 * 512 * 2;    //  1,572,864 B
  u16* Wob  = (u16*)ws;  ws += (size_t)512 * 512 * 2;     //    524,288 B
  u16* QKV  = (u16*)ws;  ws += (size_t)M_PAD * 1536 * 2;  // 25,952,256 B
  u16* ATT  = (u16*)ws;                                   //  8,650,752 B
  float* Part = (float*)Xp;  // dead after gemm1; 272*66*4 = 72 KB

  prep<<<(NCH_X + NCH_WQ + NCH_WO) / 256, 256, 0, stream>>>(
      x, wq, wk, wv, wo, Xp, Wqkv, Wob);

  gemm256<<<198, 512, 0, stream>>>(Xp, Wqkv, QKV);

  attn<<<NDB + 2048, 256, 0, stream>>>(QKV, ATT, Part);
  attn_fin<<<16, 64, 0, stream>>>(Part, ATT);

  gemm128<512, true><<<260, 256, 0, stream>>>(ATT, Wob, nullptr, out);
}

// Round 10
// 57.879 us; speedup vs baseline: 1.5376x; 1.0220x over previous
//
#include <hip/hip_runtime.h>

#define DI __device__ __forceinline__

typedef __bf16 bf16x8 __attribute__((ext_vector_type(8)));
typedef float  f32x4  __attribute__((ext_vector_type(4)));
typedef unsigned short u16;
typedef unsigned int   u32;

constexpr int BATCH  = 2;
constexpr int NNODE  = 4097;          // 64*64 grid + 1 global token
constexpr int M_REAL = BATCH * NNODE; // 8194
constexpr int M_PAD  = 8448;          // 33 * 256
constexpr int KDIM   = 512;

// dense global-token row: split-K softmax partials
constexpr int JC     = 256;                        // keys per chunk
constexpr int NCHUNK = (NNODE + JC - 1) / JC;      // 17
constexpr int NDB    = BATCH * 8 * NCHUNK;         // 272 dense phase-A blocks

DI float bf2f(u16 u)  { return __uint_as_float(((u32)u) << 16); }
DI float bflo(u32 v)  { return __uint_as_float(v << 16); }
DI float bfhi(u32 v)  { return __uint_as_float(v & 0xffff0000u); }
DI u16   f2bf(float f) {
  u32 u = __float_as_uint(f);
  u32 r = (u + 0x7fffu + ((u >> 16) & 1u)) >> 16;   // RNE
  return (u16)r;
}

DI void gload_lds16(const void* g, void* l) {
  __builtin_amdgcn_global_load_lds(
      (const __attribute__((address_space(1))) u32*)g,
      (__attribute__((address_space(3))) u32*)l, 16, 0, 0);
}

// ---------------------------------------------------------------- prep ----
constexpr int NCH_X  = M_PAD * KDIM / 8;   // 540672
constexpr int NCH_WQ = 1536 * KDIM / 8;    // 98304
constexpr int NCH_WO = 512 * KDIM / 8;     // 32768

__global__ __launch_bounds__(256) void prep(
    const float* __restrict__ x,  const float* __restrict__ wq,
    const float* __restrict__ wk, const float* __restrict__ wv,
    const float* __restrict__ wo,
    u16* __restrict__ Xp, u16* __restrict__ Wqkv, u16* __restrict__ Wob) {
  int idx = blockIdx.x * 256 + threadIdx.x;
  const float* src = nullptr;
  u16* dst = nullptr;
  bool zero = false;
  if (idx < NCH_X) {
    int row = idx >> 6;
    dst = Xp + (size_t)idx * 8;
    if (row < M_REAL) src = x + (size_t)idx * 8; else zero = true;
  } else if (idx < NCH_X + NCH_WQ) {
    int t = idx - NCH_X;
    int row = t >> 6;
    dst = Wqkv + (size_t)t * 8;
    const float* W = row < 512 ? wq : (row < 1024 ? wk : wv);
    src = W + ((size_t)(row & 511) << 9) + ((t & 63) * 8);
  } else if (idx < NCH_X + NCH_WQ + NCH_WO) {
    int t = idx - NCH_X - NCH_WQ;
    dst = Wob + (size_t)t * 8;
    src = wo + (size_t)t * 8;
  } else {
    return;
  }
  u32 o[4];
  if (zero) {
    o[0] = o[1] = o[2] = o[3] = 0u;
  } else {
    float4 f0 = ((const float4*)src)[0];
    float4 f1 = ((const float4*)src)[1];
    o[0] = (u32)f2bf(f0.x) | ((u32)f2bf(f0.y) << 16);
    o[1] = (u32)f2bf(f0.z) | ((u32)f2bf(f0.w) << 16);
    o[2] = (u32)f2bf(f1.x) | ((u32)f2bf(f1.y) << 16);
    o[3] = (u32)f2bf(f1.z) | ((u32)f2bf(f1.w) << 16);
  }
  uint4 v; v.x = o[0]; v.y = o[1]; v.z = o[2]; v.w = o[3];
  *(uint4*)dst = v;
}

// ------------------------------------------------- 256x256 dbuf GEMM ------
// (unchanged from R9 — proven, with bijective XCD swizzle)
__global__ __launch_bounds__(512, 2) void gemm256(
    const u16* __restrict__ A, const u16* __restrict__ B,
    u16* __restrict__ C) {
  __shared__ __align__(16) u16 SM[65536];
  const int tid  = threadIdx.x;
  const int lane = tid & 63;
  const int wid  = tid >> 6;
  const int wm   = wid >> 2;
  const int wn   = wid & 3;

  const int obid = blockIdx.x;            // 0..197
  const int xcd = obid & 7, loc = obid >> 3;
  const int wgid = (xcd < 6) ? xcd * 25 + loc : 150 + (xcd - 6) * 24 + loc;
  const int m0 = (wgid / 6) * 256;
  const int n0 = (wgid % 6) * 256;

  const int l15 = lane & 15, l7 = lane & 7, lg = lane >> 4;

  const int srow = tid >> 3;
  const int scol = ((tid & 7) ^ (srow & 7)) << 3;
  const u16* Ag = A + (size_t)(m0 + srow) * KDIM + scol;
  const u16* Bg = B + (size_t)(n0 + srow) * KDIM + scol;

  const int kx0 = ((lg * 8)        ^ (l7 << 3));
  const int kx1 = (((4 | lg) * 8)  ^ (l7 << 3));
  const int aBase = wm * 8192 + l15 * 64;
  const int bBase = 32768 + (wn >> 1) * 8192 + ((wn & 1) * 64 + l15) * 64;

  f32x4 acc[8][4] = {};

  constexpr int NT = KDIM / 64;

  auto stage = [&](int t, int buf) {
    const int ab = buf * 32768;
    const u16* ga = Ag + t * 64;
    const u16* gb = Bg + t * 64;
#pragma unroll
    for (int h = 0; h < 4; ++h) {
      gload_lds16(ga + (size_t)h * 64 * KDIM, (char*)SM + ab + h * 8192 + tid * 16);
      gload_lds16(gb + (size_t)h * 64 * KDIM, (char*)SM + 65536 + ab + h * 8192 + tid * 16);
    }
  };

  stage(0, 0);

  for (int t = 0; t < NT; ++t) {
    const int buf = t & 1;
    if (t + 1 < NT) {
      stage(t + 1, buf ^ 1);
      asm volatile("s_waitcnt vmcnt(8)" ::: "memory");
    } else {
      asm volatile("s_waitcnt vmcnt(0)" ::: "memory");
    }
    asm volatile("s_barrier" ::: "memory");

    const int aB = aBase + buf * 16384;
    const int bB = bBase + buf * 16384;

    bf16x8 bfr[4][2];
#pragma unroll
    for (int ni = 0; ni < 4; ++ni) {
      bfr[ni][0] = *(const bf16x8*)&SM[bB + ni * 1024 + kx0];
      bfr[ni][1] = *(const bf16x8*)&SM[bB + ni * 1024 + kx1];
    }
#pragma unroll
    for (int qm = 0; qm < 2; ++qm) {
      bf16x8 af[4][2];
#pragma unroll
      for (int i = 0; i < 4; ++i) {
        const int mi = qm * 4 + i;
        af[i][0] = *(const bf16x8*)&SM[aB + mi * 1024 + kx0];
        af[i][1] = *(const bf16x8*)&SM[aB + mi * 1024 + kx1];
      }
      __builtin_amdgcn_s_setprio(1);
#pragma unroll
      for (int i = 0; i < 4; ++i)
#pragma unroll
        for (int ni = 0; ni < 4; ++ni) {
          acc[qm*4+i][ni] = __builtin_amdgcn_mfma_f32_16x16x32_bf16(
              af[i][0], bfr[ni][0], acc[qm*4+i][ni], 0, 0, 0);
          acc[qm*4+i][ni] = __builtin_amdgcn_mfma_f32_16x16x32_bf16(
              af[i][1], bfr[ni][1], acc[qm*4+i][ni], 0, 0, 0);
        }
      __builtin_amdgcn_s_setprio(0);
    }
    asm volatile("s_barrier" ::: "memory");
  }

  const int cr = lg * 4, cc = l15;
#pragma unroll
  for (int mi = 0; mi < 8; ++mi)
#pragma unroll
    for (int j = 0; j < 4; ++j) {
      const int row = m0 + wm * 128 + mi * 16 + cr + j;
#pragma unroll
      for (int ni = 0; ni < 4; ++ni) {
        const int col = n0 + wn * 64 + ni * 16 + cc;
        C[(size_t)row * 1536 + col] = f2bf(acc[mi][ni][j]);
      }
    }
}

// --------------------- 160x128 dbuf GEMM (output, one-round grid) ---------
// 52 m-tiles x 4 n-tiles = 208 blocks <= 256 CUs -> single-round makespan
// (gemm128's 260 blocks forced 2 blocks on 4 CUs = 2x makespan).
// 4 waves (2x2), wave-tile 80x64, acc[5][4]. LDS 72KB: A 2x[160][64],
// B 2x[128][64], same XOR swizzle + counted-vmcnt-before-barrier schedule.
__global__ __launch_bounds__(256, 1) void gemm160(
    const u16* __restrict__ A, const u16* __restrict__ B,
    float* __restrict__ Cf) {
  __shared__ __align__(16) u16 SM[36864];
  const int tid  = threadIdx.x;
  const int lane = tid & 63;
  const int wid  = tid >> 6;      // 0..3
  const int wm   = wid >> 1, wn = wid & 1;

  const int obid = blockIdx.x;            // 0..207, 208 % 8 == 0
  const int wgid = (obid & 7) * 26 + (obid >> 3);
  const int m0 = (wgid >> 2) * 160;
  const int n0 = (wgid & 3) * 128;

  const int l15 = lane & 15, l7 = lane & 7, lg = lane >> 4;

  // A staging: 1280 16B-slots, 5 per thread: s = tid + 256*i
  const u16* AgP[5];
#pragma unroll
  for (int i = 0; i < 5; ++i) {
    const int s = tid + 256 * i;
    const int row = s >> 3, g = s & 7;
    AgP[i] = A + (size_t)(m0 + row) * KDIM + ((g ^ (row & 7)) << 3);
  }
  // B staging: 1024 slots, 4 per thread
  const u16* BgP[4];
#pragma unroll
  for (int i = 0; i < 4; ++i) {
    const int s = tid + 256 * i;
    const int row = s >> 3, g = s & 7;
    BgP[i] = B + (size_t)(n0 + row) * KDIM + ((g ^ (row & 7)) << 3);
  }

  const int kx0 = ((lg * 8)       ^ (l7 << 3));
  const int kx1 = (((4 | lg) * 8) ^ (l7 << 3));
  const int aBase = wm * 5120 + l15 * 64;            // elems
  const int bBase = 20480 + wn * 4096 + l15 * 64;    // B region at elem 20480

  f32x4 acc[5][4] = {};
  constexpr int NT = KDIM / 64;   // 8

  auto stage = [&](int t, int buf) {
#pragma unroll
    for (int i = 0; i < 5; ++i)
      gload_lds16(AgP[i] + t * 64,
                  (char*)SM + buf * 20480 + (tid + 256 * i) * 16);
#pragma unroll
    for (int i = 0; i < 4; ++i)
      gload_lds16(BgP[i] + t * 64,
                  (char*)SM + 40960 + buf * 16384 + (tid + 256 * i) * 16);
  };

  stage(0, 0);

  for (int t = 0; t < NT; ++t) {
    const int buf = t & 1;
    if (t + 1 < NT) {
      stage(t + 1, buf ^ 1);
      asm volatile("s_waitcnt vmcnt(9)" ::: "memory");  // drain tile t's 9 loads
    } else {
      asm volatile("s_waitcnt vmcnt(0)" ::: "memory");
    }
    asm volatile("s_barrier" ::: "memory");

    const int aB = aBase + buf * 10240;   // elems
    const int bB = bBase + buf * 8192;

    bf16x8 bfr[4][2];
#pragma unroll
    for (int ni = 0; ni < 4; ++ni) {
      bfr[ni][0] = *(const bf16x8*)&SM[bB + ni * 1024 + kx0];
      bfr[ni][1] = *(const bf16x8*)&SM[bB + ni * 1024 + kx1];
    }
    bf16x8 af[5][2];
#pragma unroll
    for (int i = 0; i < 5; ++i) {
      af[i][0] = *(const bf16x8*)&SM[aB + i * 1024 + kx0];
      af[i][1] = *(const bf16x8*)&SM[aB + i * 1024 + kx1];
    }
    __builtin_amdgcn_s_setprio(1);
#pragma unroll
    for (int i = 0; i < 5; ++i)
#pragma unroll
      for (int ni = 0; ni < 4; ++ni) {
        acc[i][ni] = __builtin_amdgcn_mfma_f32_16x16x32_bf16(
            af[i][0], bfr[ni][0], acc[i][ni], 0, 0, 0);
        acc[i][ni] = __builtin_amdgcn_mfma_f32_16x16x32_bf16(
            af[i][1], bfr[ni][1], acc[i][ni], 0, 0, 0);
      }
    __builtin_amdgcn_s_setprio(0);
    asm volatile("s_barrier" ::: "memory");
  }

  const int cr = lg * 4, cc = l15;
#pragma unroll
  for (int mi = 0; mi < 5; ++mi)
#pragma unroll
    for (int j = 0; j < 4; ++j) {
      const int row = m0 + wm * 80 + mi * 16 + cr + j;
      if (row >= M_REAL) continue;      // rows 8194.. are poison A; never write
#pragma unroll
      for (int ni = 0; ni < 4; ++ni) {
        const int col = n0 + wn * 64 + ni * 16 + cc;
        Cf[(size_t)row * 512 + col] = acc[mi][ni][j];
      }
    }
}

// ------------------------------------------------------------ attention ----
// blocks [0,NDB): dense-row phase A (split-K partials -> Part)
// blocks [NDB,..): sparse rows, one wave per (b, node), XCD-chunked swizzle.
// NO intra-kernel merge election (R6/R8: election costs 20-30 us chip-wide).
__global__ __launch_bounds__(256) void attn(const u16* __restrict__ QKV,
                                            u16* __restrict__ O,
                                            float* __restrict__ Part) {
  const int tid = threadIdx.x;
  if (blockIdx.x < NDB) {
    __shared__ float qs[64];
    __shared__ float ev[JC];
    __shared__ float red[256];
    const int db = blockIdx.x;
    const int b  = db / (8 * NCHUNK);
    const int rm = db % (8 * NCHUNK);
    const int h  = rm / NCHUNK;
    const int ch = rm % NCHUNK;
    const int j0 = ch * JC;
    const size_t base = (size_t)b * NNODE;

    if (tid < 64) qs[tid] = bf2f(QKV[base * 1536 + h * 64 + tid]);
    __syncthreads();

    const int j = j0 + tid;
    float s = -3e38f;
    if (j < NNODE) {
      const uint4* kp4 = (const uint4*)(QKV + (base + j) * 1536 + 512 + h * 64);
      float a = 0.f;
#pragma unroll
      for (int q8 = 0; q8 < 8; ++q8) {
        uint4 kv = kp4[q8];
        int d = q8 * 8;
        a += qs[d+0]*bflo(kv.x) + qs[d+1]*bfhi(kv.x)
           + qs[d+2]*bflo(kv.y) + qs[d+3]*bfhi(kv.y)
           + qs[d+4]*bflo(kv.z) + qs[d+5]*bfhi(kv.z)
           + qs[d+6]*bflo(kv.w) + qs[d+7]*bfhi(kv.w);
      }
      s = a * 0.125f;
    }
    red[tid] = s;
    __syncthreads();
    for (int st = 128; st > 0; st >>= 1) {
      if (tid < st) red[tid] = fmaxf(red[tid], red[tid + st]);
      __syncthreads();
    }
    const float mx = red[0];
    __syncthreads();
    const float e = (j < NNODE) ? __expf(s - mx) : 0.f;
    ev[tid] = e;
    red[tid] = e;
    __syncthreads();
    for (int st = 128; st > 0; st >>= 1) {
      if (tid < st) red[tid] += red[tid + st];
      __syncthreads();
    }
    const float ssum = red[0];
    __syncthreads();

    const int w = tid >> 6, lane = tid & 63;
    const int js = lane >> 3, dg = lane & 7;
    float oa[8] = {};
#pragma unroll
    for (int jj = 0; jj < 8; ++jj) {
      const int li = w * 64 + jj * 8 + js;
      const int jv = j0 + li;
      if (jv < NNODE) {
        const float we = ev[li];
        const uint4 vv = *(const uint4*)(QKV + (base + jv) * 1536 + 1024 + h * 64 + dg * 8);
        oa[0] += we * bflo(vv.x); oa[1] += we * bfhi(vv.x);
        oa[2] += we * bflo(vv.y); oa[3] += we * bfhi(vv.y);
        oa[4] += we * bflo(vv.z); oa[5] += we * bfhi(vv.z);
        oa[6] += we * bflo(vv.w); oa[7] += we * bfhi(vv.w);
      }
    }
#pragma unroll
    for (int m = 8; m <= 32; m <<= 1)
#pragma unroll
      for (int t = 0; t < 8; ++t) oa[t] += __shfl_xor(oa[t], m);
    __syncthreads();
    if (lane < 8) {
#pragma unroll
      for (int t = 0; t < 8; ++t) red[w * 64 + lane * 8 + t] = oa[t];
    }
    __syncthreads();
    float* P = Part + ((size_t)((b * 8 + h) * NCHUNK + ch)) * 66;
    if (tid == 0) { P[0] = mx; P[1] = ssum; }
    if (tid < 64)
      P[2 + tid] = red[tid] + red[64 + tid] + red[128 + tid] + red[192 + tid];
    return;
  }

  // ---- sparse rows ----
  const int obid = blockIdx.x - NDB;                    // 0..2047
  const int sb   = ((obid & 7) << 8) | (obid >> 3);     // bijective (2048 % 8 == 0)
  const int wid  = sb * 4 + (tid >> 6);                 // 0..8191
  const int lane = tid & 63;
  const int b = wid >> 12;
  const int g = wid & 4095;
  const int i = g + 1;
  const int r = g >> 6, c = g & 63;
  const size_t base = (size_t)b * NNODE;

  int  jn[6];
  bool vd[6];
  jn[0] = 0;                     vd[0] = true;
  jn[1] = i;                     vd[1] = true;
  jn[2] = (c > 0)  ? i - 1  : i; vd[2] = (c > 0);
  jn[3] = (c < 63) ? i + 1  : i; vd[3] = (c < 63);
  jn[4] = (r > 0)  ? i - 64 : i; vd[4] = (r > 0);
  jn[5] = (r < 63) ? i + 64 : i; vd[5] = (r < 63);

  const uint4 qv = *(const uint4*)(QKV + (base + i) * 1536 + lane * 8);
  float qf[8] = { bflo(qv.x), bfhi(qv.x), bflo(qv.y), bfhi(qv.y),
                  bflo(qv.z), bfhi(qv.z), bflo(qv.w), bfhi(qv.w) };

  float sc[6];
#pragma unroll
  for (int n = 0; n < 6; ++n) {
    const uint4 kv = *(const uint4*)(QKV + (base + jn[n]) * 1536 + 512 + lane * 8);
    float p = qf[0]*bflo(kv.x) + qf[1]*bfhi(kv.x)
            + qf[2]*bflo(kv.y) + qf[3]*bfhi(kv.y)
            + qf[4]*bflo(kv.z) + qf[5]*bfhi(kv.z)
            + qf[6]*bflo(kv.w) + qf[7]*bfhi(kv.w);
    p += __shfl_xor(p, 1);
    p += __shfl_xor(p, 2);
    p += __shfl_xor(p, 4);
    sc[n] = p * 0.125f;
  }
  float mx = -1e30f;
#pragma unroll
  for (int n = 0; n < 6; ++n) if (vd[n]) mx = fmaxf(mx, sc[n]);
  float pw[6], den = 0.f;
#pragma unroll
  for (int n = 0; n < 6; ++n) {
    pw[n] = vd[n] ? __expf(sc[n] - mx) : 0.f;
    den += pw[n];
  }
  const float inv = 1.f / den;

  float oa[8] = {};
#pragma unroll
  for (int n = 0; n < 6; ++n) {
    const uint4 vv = *(const uint4*)(QKV + (base + jn[n]) * 1536 + 1024 + lane * 8);
    const float w = pw[n];
    oa[0] += w * bflo(vv.x); oa[1] += w * bfhi(vv.x);
    oa[2] += w * bflo(vv.y); oa[3] += w * bfhi(vv.y);
    oa[4] += w * bflo(vv.z); oa[5] += w * bfhi(vv.z);
    oa[6] += w * bflo(vv.w); oa[7] += w * bfhi(vv.w);
  }
  uint4 ov;
  ov.x = (u32)f2bf(oa[0] * inv) | ((u32)f2bf(oa[1] * inv) << 16);
  ov.y = (u32)f2bf(oa[2] * inv) | ((u32)f2bf(oa[3] * inv) << 16);
  ov.z = (u32)f2bf(oa[4] * inv) | ((u32)f2bf(oa[5] * inv) << 16);
  ov.w = (u32)f2bf(oa[6] * inv) | ((u32)f2bf(oa[7] * inv) << 16);
  *(uint4*)(O + (base + i) * 512 + lane * 8) = ov;
}

// phase B: merge the NCHUNK partials per (b,h), write O row 0 (16 parallel blocks).
__global__ __launch_bounds__(64) void attn_fin(const float* __restrict__ Part,
                                               u16* __restrict__ O) {
  const int b = blockIdx.x >> 3, h = blockIdx.x & 7;
  const int d = threadIdx.x;
  const float* P = Part + ((size_t)(b * 8 + h) * NCHUNK) * 66;
  float m = -3e38f;
  for (int c = 0; c < NCHUNK; ++c) m = fmaxf(m, P[c * 66]);
  float s = 0.f, o = 0.f;
  for (int c = 0; c < NCHUNK; ++c) {
    const float ex = __expf(P[c * 66] - m);
    s += P[c * 66 + 1] * ex;
    o += P[c * 66 + 2 + d] * ex;
  }
  O[(size_t)b * NNODE * 512 + h * 64 + d] = f2bf(o / s);
}

// -------------------------------------------------------------- launch ----
extern "C" void kernel_launch(void* const* d_in, const int* in_sizes, int n_in,
                              void* d_out, int out_size, void* d_ws, size_t ws_size,
                              hipStream_t stream) {
  (void)in_sizes; (void)n_in; (void)out_size; (void)ws_size;
  const float* x  = (const float*)d_in[0];
  const float* wq = (const float*)d_in[1];
  const float* wk = (const float*)d_in[2];
  const float* wv = (const float*)d_in[3];
  const float* wo = (const float*)d_in[4];
  float* out = (float*)d_out;

  char* ws = (char*)d_ws;
  u16* Xp   = (u16*)ws;  ws += (size_t)M_PAD * 512 * 2;   //  8,650,752 B
  u16* Wqkv = (u16*)ws;  ws += (size_t)1536 * 512 * 2;    //  1,572,864 B
  u16* Wob  = (u16*)ws;  ws += (size_t)512 * 512 * 2;     //    524,288 B
  u16* QKV  = (u16*)ws;  ws += (size_t)M_PAD * 1536 * 2;  // 25,952,256 B
  u16* ATT  = (u16*)ws;                                   //  8,650,752 B
  float* Part = (float*)Xp;  // dead after gemm1; 272*66*4 = 72 KB

  prep<<<(NCH_X + NCH_WQ + NCH_WO) / 256, 256, 0, stream>>>(
      x, wq, wk, wv, wo, Xp, Wqkv, Wob);

  gemm256<<<198, 512, 0, stream>>>(Xp, Wqkv, QKV);

  attn<<<NDB + 2048, 256, 0, stream>>>(QKV, ATT, Part);
  attn_fin<<<16, 64, 0, stream>>>(Part, ATT);

  gemm160<<<208, 256, 0, stream>>>(ATT, Wob, out);
}

// Round 12
// 55.769 us; speedup vs baseline: 1.5958x; 1.0378x over previous
//
#include <hip/hip_runtime.h>

#define DI __device__ __forceinline__

typedef __bf16 bf16x8 __attribute__((ext_vector_type(8)));
typedef float  f32x4  __attribute__((ext_vector_type(4)));
typedef unsigned short u16;
typedef unsigned int   u32;

constexpr int BATCH  = 2;
constexpr int NNODE  = 4097;          // 64*64 grid + 1 global token
constexpr int M_REAL = BATCH * NNODE; // 8194
constexpr int M_PAD  = 8448;          // padded rows in Xp/QKV buffers
constexpr int KDIM   = 512;

// dense global-token row: split-K softmax partials
constexpr int JC     = 256;                        // keys per chunk
constexpr int NCHUNK = (NNODE + JC - 1) / JC;      // 17
constexpr int NDB    = BATCH * 8 * NCHUNK;         // 272 dense phase-A blocks

DI float bf2f(u16 u)  { return __uint_as_float(((u32)u) << 16); }
DI float bflo(u32 v)  { return __uint_as_float(v << 16); }
DI float bfhi(u32 v)  { return __uint_as_float(v & 0xffff0000u); }
DI u16   f2bf(float f) {
  u32 u = __float_as_uint(f);
  u32 r = (u + 0x7fffu + ((u >> 16) & 1u)) >> 16;   // RNE
  return (u16)r;
}

DI void gload_lds16(const void* g, void* l) {
  __builtin_amdgcn_global_load_lds(
      (const __attribute__((address_space(1))) u32*)g,
      (__attribute__((address_space(3))) u32*)l, 16, 0, 0);
}

// ---------------------------------------------------------------- prep ----
constexpr int NCH_X  = M_PAD * KDIM / 8;   // 540672
constexpr int NCH_WQ = 1536 * KDIM / 8;    // 98304
constexpr int NCH_WO = 512 * KDIM / 8;     // 32768

__global__ __launch_bounds__(256) void prep(
    const float* __restrict__ x,  const float* __restrict__ wq,
    const float* __restrict__ wk, const float* __restrict__ wv,
    const float* __restrict__ wo,
    u16* __restrict__ Xp, u16* __restrict__ Wqkv, u16* __restrict__ Wob) {
  int idx = blockIdx.x * 256 + threadIdx.x;
  const float* src = nullptr;
  u16* dst = nullptr;
  bool zero = false;
  if (idx < NCH_X) {
    int row = idx >> 6;
    dst = Xp + (size_t)idx * 8;
    if (row < M_REAL) src = x + (size_t)idx * 8; else zero = true;
  } else if (idx < NCH_X + NCH_WQ) {
    int t = idx - NCH_X;
    int row = t >> 6;
    dst = Wqkv + (size_t)t * 8;
    const float* W = row < 512 ? wq : (row < 1024 ? wk : wv);
    src = W + ((size_t)(row & 511) << 9) + ((t & 63) * 8);
  } else if (idx < NCH_X + NCH_WQ + NCH_WO) {
    int t = idx - NCH_X - NCH_WQ;
    dst = Wob + (size_t)t * 8;
    src = wo + (size_t)t * 8;
  } else {
    return;
  }
  u32 o[4];
  if (zero) {
    o[0] = o[1] = o[2] = o[3] = 0u;
  } else {
    float4 f0 = ((const float4*)src)[0];
    float4 f1 = ((const float4*)src)[1];
    o[0] = (u32)f2bf(f0.x) | ((u32)f2bf(f0.y) << 16);
    o[1] = (u32)f2bf(f0.z) | ((u32)f2bf(f0.w) << 16);
    o[2] = (u32)f2bf(f1.x) | ((u32)f2bf(f1.y) << 16);
    o[3] = (u32)f2bf(f1.z) | ((u32)f2bf(f1.w) << 16);
  }
  uint4 v; v.x = o[0]; v.y = o[1]; v.z = o[2]; v.w = o[3];
  *(uint4*)dst = v;
}

// ------------------------------------------------- 224x256 dbuf GEMM ------
// QKV GEMM: BM=224 -> 37x6 = 222 blocks <= 256 CUs (one-round makespan).
// 8 waves (2M x 4N), wave-tile 112x64, acc[7][4]. LDS 120KB: A 2x[224][64],
// B 2x[256][64]. Staged-bytes audit: A = 1792 slots x 16B = 28672 B ✓,
// B = 2048 slots x 16B = 32768 B ✓ (R11 NaN bug: B had only 1024 slots).
// Per-tile loads: waves 0-3 = 8 (3A+1A+4B), waves 4-7 = 7 (3A+4B) ->
// wave-uniform counted drains vmcnt(8)/vmcnt(7) BEFORE the barrier.
__global__ __launch_bounds__(512, 2) void gemm224(
    const u16* __restrict__ A, const u16* __restrict__ B,
    u16* __restrict__ C) {
  __shared__ __align__(16) u16 SM[61440];  // A bytes [0,57344), B [57344,122880)
  const int tid  = threadIdx.x;
  const int lane = tid & 63;
  const int wid  = tid >> 6;
  const int wm   = wid >> 2;   // 0..1
  const int wn   = wid & 3;    // 0..3

  const int obid = blockIdx.x;            // 0..221; 222 = 8*27+6
  const int xcd = obid & 7, loc = obid >> 3;
  const int wgid = (xcd < 6) ? xcd * 28 + loc : 168 + (xcd - 6) * 27 + loc;
  const int m0 = (wgid / 6) * 224;
  const int n0 = (wgid % 6) * 256;

  const int l15 = lane & 15, l7 = lane & 7, lg = lane >> 4;

  // A staging: 1792 slots (slot s: row s>>3, lds-granule s&7, pre-swizzled src)
  const u16* AgP[4];
#pragma unroll
  for (int i = 0; i < 3; ++i) {
    const int s = tid + 512 * i;
    const int row = s >> 3, g = s & 7;
    AgP[i] = A + (size_t)(m0 + row) * KDIM + ((g ^ (row & 7)) << 3);
  }
  {
    const int s = 1536 + (tid & 255);        // used only by tid < 256
    const int row = s >> 3, g = s & 7;
    AgP[3] = A + (size_t)(m0 + row) * KDIM + ((g ^ (row & 7)) << 3);
  }
  // B staging: 2048 slots (256 rows), 4 per thread
  const u16* BgP[4];
#pragma unroll
  for (int i = 0; i < 4; ++i) {
    const int s = tid + 512 * i;
    const int row = s >> 3, g = s & 7;
    BgP[i] = B + (size_t)(n0 + row) * KDIM + ((g ^ (row & 7)) << 3);
  }

  const int kx0 = ((lg * 8)       ^ (l7 << 3));
  const int kx1 = (((4 | lg) * 8) ^ (l7 << 3));
  const int aBase = wm * 7168 + l15 * 64;             // elems (112 rows/wave)
  const int bBase = 28672 + wn * 4096 + l15 * 64;     // B region at elem 28672

  f32x4 acc[7][4] = {};
  constexpr int NT = KDIM / 64;   // 8

  auto stage = [&](int t, int buf) {
#pragma unroll
    for (int i = 0; i < 3; ++i)
      gload_lds16(AgP[i] + t * 64,
                  (char*)SM + buf * 28672 + (tid + 512 * i) * 16);
    if (tid < 256)
      gload_lds16(AgP[3] + t * 64,
                  (char*)SM + buf * 28672 + (1536 + tid) * 16);
#pragma unroll
    for (int i = 0; i < 4; ++i)
      gload_lds16(BgP[i] + t * 64,
                  (char*)SM + 57344 + buf * 32768 + (tid + 512 * i) * 16);
  };

  stage(0, 0);

  for (int t = 0; t < NT; ++t) {
    const int buf = t & 1;
    if (t + 1 < NT) {
      stage(t + 1, buf ^ 1);
      // drain tile t's loads only (wave-uniform branch)
      if (tid < 256) asm volatile("s_waitcnt vmcnt(8)" ::: "memory");
      else           asm volatile("s_waitcnt vmcnt(7)" ::: "memory");
    } else {
      asm volatile("s_waitcnt vmcnt(0)" ::: "memory");
    }
    asm volatile("s_barrier" ::: "memory");  // all waves: tile t resident

    const int aB = aBase + buf * 14336;   // elems
    const int bB = bBase + buf * 16384;

    bf16x8 bfr[4][2];
#pragma unroll
    for (int ni = 0; ni < 4; ++ni) {
      bfr[ni][0] = *(const bf16x8*)&SM[bB + ni * 1024 + kx0];
      bfr[ni][1] = *(const bf16x8*)&SM[bB + ni * 1024 + kx1];
    }
    // qm half 0: mi 0..3
    {
      bf16x8 af[4][2];
#pragma unroll
      for (int i = 0; i < 4; ++i) {
        af[i][0] = *(const bf16x8*)&SM[aB + i * 1024 + kx0];
        af[i][1] = *(const bf16x8*)&SM[aB + i * 1024 + kx1];
      }
      __builtin_amdgcn_s_setprio(1);
#pragma unroll
      for (int i = 0; i < 4; ++i)
#pragma unroll
        for (int ni = 0; ni < 4; ++ni) {
          acc[i][ni] = __builtin_amdgcn_mfma_f32_16x16x32_bf16(
              af[i][0], bfr[ni][0], acc[i][ni], 0, 0, 0);
          acc[i][ni] = __builtin_amdgcn_mfma_f32_16x16x32_bf16(
              af[i][1], bfr[ni][1], acc[i][ni], 0, 0, 0);
        }
      __builtin_amdgcn_s_setprio(0);
    }
    // qm half 1: mi 4..6
    {
      bf16x8 af[3][2];
#pragma unroll
      for (int i = 0; i < 3; ++i) {
        af[i][0] = *(const bf16x8*)&SM[aB + (4 + i) * 1024 + kx0];
        af[i][1] = *(const bf16x8*)&SM[aB + (4 + i) * 1024 + kx1];
      }
      __builtin_amdgcn_s_setprio(1);
#pragma unroll
      for (int i = 0; i < 3; ++i)
#pragma unroll
        for (int ni = 0; ni < 4; ++ni) {
          acc[4+i][ni] = __builtin_amdgcn_mfma_f32_16x16x32_bf16(
              af[i][0], bfr[ni][0], acc[4+i][ni], 0, 0, 0);
          acc[4+i][ni] = __builtin_amdgcn_mfma_f32_16x16x32_bf16(
              af[i][1], bfr[ni][1], acc[4+i][ni], 0, 0, 0);
        }
      __builtin_amdgcn_s_setprio(0);
    }
    asm volatile("s_barrier" ::: "memory");  // reads done before buf reuse
  }

  const int cr = lg * 4, cc = l15;
#pragma unroll
  for (int mi = 0; mi < 7; ++mi)
#pragma unroll
    for (int j = 0; j < 4; ++j) {
      const int row = m0 + wm * 112 + mi * 16 + cr + j;  // < 8288 <= M_PAD
#pragma unroll
      for (int ni = 0; ni < 4; ++ni) {
        const int col = n0 + wn * 64 + ni * 16 + cc;
        C[(size_t)row * 1536 + col] = f2bf(acc[mi][ni][j]);
      }
    }
}

// --------------------- 160x128 dbuf GEMM (output, one-round grid) ---------
// (unchanged from R10 — 208 blocks, single-round makespan, -1.3us proven)
__global__ __launch_bounds__(256, 1) void gemm160(
    const u16* __restrict__ A, const u16* __restrict__ B,
    float* __restrict__ Cf) {
  __shared__ __align__(16) u16 SM[36864];
  const int tid  = threadIdx.x;
  const int lane = tid & 63;
  const int wid  = tid >> 6;      // 0..3
  const int wm   = wid >> 1, wn = wid & 1;

  const int obid = blockIdx.x;            // 0..207, 208 % 8 == 0
  const int wgid = (obid & 7) * 26 + (obid >> 3);
  const int m0 = (wgid >> 2) * 160;
  const int n0 = (wgid & 3) * 128;

  const int l15 = lane & 15, l7 = lane & 7, lg = lane >> 4;

  const u16* AgP[5];
#pragma unroll
  for (int i = 0; i < 5; ++i) {
    const int s = tid + 256 * i;
    const int row = s >> 3, g = s & 7;
    AgP[i] = A + (size_t)(m0 + row) * KDIM + ((g ^ (row & 7)) << 3);
  }
  const u16* BgP[4];
#pragma unroll
  for (int i = 0; i < 4; ++i) {
    const int s = tid + 256 * i;
    const int row = s >> 3, g = s & 7;
    BgP[i] = B + (size_t)(n0 + row) * KDIM + ((g ^ (row & 7)) << 3);
  }

  const int kx0 = ((lg * 8)       ^ (l7 << 3));
  const int kx1 = (((4 | lg) * 8) ^ (l7 << 3));
  const int aBase = wm * 5120 + l15 * 64;
  const int bBase = 20480 + wn * 4096 + l15 * 64;

  f32x4 acc[5][4] = {};
  constexpr int NT = KDIM / 64;   // 8

  auto stage = [&](int t, int buf) {
#pragma unroll
    for (int i = 0; i < 5; ++i)
      gload_lds16(AgP[i] + t * 64,
                  (char*)SM + buf * 20480 + (tid + 256 * i) * 16);
#pragma unroll
    for (int i = 0; i < 4; ++i)
      gload_lds16(BgP[i] + t * 64,
                  (char*)SM + 40960 + buf * 16384 + (tid + 256 * i) * 16);
  };

  stage(0, 0);

  for (int t = 0; t < NT; ++t) {
    const int buf = t & 1;
    if (t + 1 < NT) {
      stage(t + 1, buf ^ 1);
      asm volatile("s_waitcnt vmcnt(9)" ::: "memory");
    } else {
      asm volatile("s_waitcnt vmcnt(0)" ::: "memory");
    }
    asm volatile("s_barrier" ::: "memory");

    const int aB = aBase + buf * 10240;
    const int bB = bBase + buf * 8192;

    bf16x8 bfr[4][2];
#pragma unroll
    for (int ni = 0; ni < 4; ++ni) {
      bfr[ni][0] = *(const bf16x8*)&SM[bB + ni * 1024 + kx0];
      bfr[ni][1] = *(const bf16x8*)&SM[bB + ni * 1024 + kx1];
    }
    bf16x8 af[5][2];
#pragma unroll
    for (int i = 0; i < 5; ++i) {
      af[i][0] = *(const bf16x8*)&SM[aB + i * 1024 + kx0];
      af[i][1] = *(const bf16x8*)&SM[aB + i * 1024 + kx1];
    }
    __builtin_amdgcn_s_setprio(1);
#pragma unroll
    for (int i = 0; i < 5; ++i)
#pragma unroll
      for (int ni = 0; ni < 4; ++ni) {
        acc[i][ni] = __builtin_amdgcn_mfma_f32_16x16x32_bf16(
            af[i][0], bfr[ni][0], acc[i][ni], 0, 0, 0);
        acc[i][ni] = __builtin_amdgcn_mfma_f32_16x16x32_bf16(
            af[i][1], bfr[ni][1], acc[i][ni], 0, 0, 0);
      }
    __builtin_amdgcn_s_setprio(0);
    asm volatile("s_barrier" ::: "memory");
  }

  const int cr = lg * 4, cc = l15;
#pragma unroll
  for (int mi = 0; mi < 5; ++mi)
#pragma unroll
    for (int j = 0; j < 4; ++j) {
      const int row = m0 + wm * 80 + mi * 16 + cr + j;
      if (row >= M_REAL) continue;
#pragma unroll
      for (int ni = 0; ni < 4; ++ni) {
        const int col = n0 + wn * 64 + ni * 16 + cc;
        Cf[(size_t)row * 512 + col] = acc[mi][ni][j];
      }
    }
}

// ------------------------------------------------------------ attention ----
// (unchanged from R10) blocks [0,NDB): dense-row phase A; [NDB,..): sparse.
// NO intra-kernel merge election (R6/R8: election costs 20-30 us chip-wide).
__global__ __launch_bounds__(256) void attn(const u16* __restrict__ QKV,
                                            u16* __restrict__ O,
                                            float* __restrict__ Part) {
  const int tid = threadIdx.x;
  if (blockIdx.x < NDB) {
    __shared__ float qs[64];
    __shared__ float ev[JC];
    __shared__ float red[256];
    const int db = blockIdx.x;
    const int b  = db / (8 * NCHUNK);
    const int rm = db % (8 * NCHUNK);
    const int h  = rm / NCHUNK;
    const int ch = rm % NCHUNK;
    const int j0 = ch * JC;
    const size_t base = (size_t)b * NNODE;

    if (tid < 64) qs[tid] = bf2f(QKV[base * 1536 + h * 64 + tid]);
    __syncthreads();

    const int j = j0 + tid;
    float s = -3e38f;
    if (j < NNODE) {
      const uint4* kp4 = (const uint4*)(QKV + (base + j) * 1536 + 512 + h * 64);
      float a = 0.f;
#pragma unroll
      for (int q8 = 0; q8 < 8; ++q8) {
        uint4 kv = kp4[q8];
        int d = q8 * 8;
        a += qs[d+0]*bflo(kv.x) + qs[d+1]*bfhi(kv.x)
           + qs[d+2]*bflo(kv.y) + qs[d+3]*bfhi(kv.y)
           + qs[d+4]*bflo(kv.z) + qs[d+5]*bfhi(kv.z)
           + qs[d+6]*bflo(kv.w) + qs[d+7]*bfhi(kv.w);
      }
      s = a * 0.125f;
    }
    red[tid] = s;
    __syncthreads();
    for (int st = 128; st > 0; st >>= 1) {
      if (tid < st) red[tid] = fmaxf(red[tid], red[tid + st]);
      __syncthreads();
    }
    const float mx = red[0];
    __syncthreads();
    const float e = (j < NNODE) ? __expf(s - mx) : 0.f;
    ev[tid] = e;
    red[tid] = e;
    __syncthreads();
    for (int st = 128; st > 0; st >>= 1) {
      if (tid < st) red[tid] += red[tid + st];
      __syncthreads();
    }
    const float ssum = red[0];
    __syncthreads();

    const int w = tid >> 6, lane = tid & 63;
    const int js = lane >> 3, dg = lane & 7;
    float oa[8] = {};
#pragma unroll
    for (int jj = 0; jj < 8; ++jj) {
      const int li = w * 64 + jj * 8 + js;
      const int jv = j0 + li;
      if (jv < NNODE) {
        const float we = ev[li];
        const uint4 vv = *(const uint4*)(QKV + (base + jv) * 1536 + 1024 + h * 64 + dg * 8);
        oa[0] += we * bflo(vv.x); oa[1] += we * bfhi(vv.x);
        oa[2] += we * bflo(vv.y); oa[3] += we * bfhi(vv.y);
        oa[4] += we * bflo(vv.z); oa[5] += we * bfhi(vv.z);
        oa[6] += we * bflo(vv.w); oa[7] += we * bfhi(vv.w);
      }
    }
#pragma unroll
    for (int m = 8; m <= 32; m <<= 1)
#pragma unroll
      for (int t = 0; t < 8; ++t) oa[t] += __shfl_xor(oa[t], m);
    __syncthreads();
    if (lane < 8) {
#pragma unroll
      for (int t = 0; t < 8; ++t) red[w * 64 + lane * 8 + t] = oa[t];
    }
    __syncthreads();
    float* P = Part + ((size_t)((b * 8 + h) * NCHUNK + ch)) * 66;
    if (tid == 0) { P[0] = mx; P[1] = ssum; }
    if (tid < 64)
      P[2 + tid] = red[tid] + red[64 + tid] + red[128 + tid] + red[192 + tid];
    return;
  }

  // ---- sparse rows ----
  const int obid = blockIdx.x - NDB;                    // 0..2047
  const int sb   = ((obid & 7) << 8) | (obid >> 3);     // bijective (2048 % 8 == 0)
  const int wid  = sb * 4 + (tid >> 6);                 // 0..8191
  const int lane = tid & 63;
  const int b = wid >> 12;
  const int g = wid & 4095;
  const int i = g + 1;
  const int r = g >> 6, c = g & 63;
  const size_t base = (size_t)b * NNODE;

  int  jn[6];
  bool vd[6];
  jn[0] = 0;                     vd[0] = true;
  jn[1] = i;                     vd[1] = true;
  jn[2] = (c > 0)  ? i - 1  : i; vd[2] = (c > 0);
  jn[3] = (c < 63) ? i + 1  : i; vd[3] = (c < 63);
  jn[4] = (r > 0)  ? i - 64 : i; vd[4] = (r > 0);
  jn[5] = (r < 63) ? i + 64 : i; vd[5] = (r < 63);

  const uint4 qv = *(const uint4*)(QKV + (base + i) * 1536 + lane * 8);
  float qf[8] = { bflo(qv.x), bfhi(qv.x), bflo(qv.y), bfhi(qv.y),
                  bflo(qv.z), bfhi(qv.z), bflo(qv.w), bfhi(qv.w) };

  float sc[6];
#pragma unroll
  for (int n = 0; n < 6; ++n) {
    const uint4 kv = *(const uint4*)(QKV + (base + jn[n]) * 1536 + 512 + lane * 8);
    float p = qf[0]*bflo(kv.x) + qf[1]*bfhi(kv.x)
            + qf[2]*bflo(kv.y) + qf[3]*bfhi(kv.y)
            + qf[4]*bflo(kv.z) + qf[5]*bfhi(kv.z)
            + qf[6]*bflo(kv.w) + qf[7]*bfhi(kv.w);
    p += __shfl_xor(p, 1);
    p += __shfl_xor(p, 2);
    p += __shfl_xor(p, 4);
    sc[n] = p * 0.125f;
  }
  float mx = -1e30f;
#pragma unroll
  for (int n = 0; n < 6; ++n) if (vd[n]) mx = fmaxf(mx, sc[n]);
  float pw[6], den = 0.f;
#pragma unroll
  for (int n = 0; n < 6; ++n) {
    pw[n] = vd[n] ? __expf(sc[n] - mx) : 0.f;
    den += pw[n];
  }
  const float inv = 1.f / den;

  float oa[8] = {};
#pragma unroll
  for (int n = 0; n < 6; ++n) {
    const uint4 vv = *(const uint4*)(QKV + (base + jn[n]) * 1536 + 1024 + lane * 8);
    const float w = pw[n];
    oa[0] += w * bflo(vv.x); oa[1] += w * bfhi(vv.x);
    oa[2] += w * bflo(vv.y); oa[3] += w * bfhi(vv.y);
    oa[4] += w * bflo(vv.z); oa[5] += w * bfhi(vv.z);
    oa[6] += w * bflo(vv.w); oa[7] += w * bfhi(vv.w);
  }
  uint4 ov;
  ov.x = (u32)f2bf(oa[0] * inv) | ((u32)f2bf(oa[1] * inv) << 16);
  ov.y = (u32)f2bf(oa[2] * inv) | ((u32)f2bf(oa[3] * inv) << 16);
  ov.z = (u32)f2bf(oa[4] * inv) | ((u32)f2bf(oa[5] * inv) << 16);
  ov.w = (u32)f2bf(oa[6] * inv) | ((u32)f2bf(oa[7] * inv) << 16);
  *(uint4*)(O + (base + i) * 512 + lane * 8) = ov;
}

// phase B: merge the NCHUNK partials per (b,h), write O row 0 (16 parallel blocks).
__global__ __launch_bounds__(64) void attn_fin(const float* __restrict__ Part,
                                               u16* __restrict__ O) {
  const int b = blockIdx.x >> 3, h = blockIdx.x & 7;
  const int d = threadIdx.x;
  const float* P = Part + ((size_t)(b * 8 + h) * NCHUNK) * 66;
  float m = -3e38f;
  for (int c = 0; c < NCHUNK; ++c) m = fmaxf(m, P[c * 66]);
  float s = 0.f, o = 0.f;
  for (int c = 0; c < NCHUNK; ++c) {
    const float ex = __expf(P[c * 66] - m);
    s += P[c * 66 + 1] * ex;
    o += P[c * 66 + 2 + d] * ex;
  }
  O[(size_t)b * NNODE * 512 + h * 64 + d] = f2bf(o / s);
}

// -------------------------------------------------------------- launch ----
extern "C" void kernel_launch(void* const* d_in, const int* in_sizes, int n_in,
                              void* d_out, int out_size, void* d_ws, size_t ws_size,
                              hipStream_t stream) {
  (void)in_sizes; (void)n_in; (void)out_size; (void)ws_size;
  const float* x  = (const float*)d_in[0];
  const float* wq = (const float*)d_in[1];
  const float* wk = (const float*)d_in[2];
  const float* wv = (const float*)d_in[3];
  const float* wo = (const float*)d_in[4];
  float* out = (float*)d_out;

  char* ws = (char*)d_ws;
  u16* Xp   = (u16*)ws;  ws += (size_t)M_PAD * 512 * 2;   //  8,650,752 B
  u16* Wqkv = (u16*)ws;  ws += (size_t)1536 * 512 * 2;    //  1,572,864 B
  u16* Wob  = (u16*)ws;  ws += (size_t)512 * 512 * 2;     //    524,288 B
  u16* QKV  = (u16*)ws;  ws += (size_t)M_PAD * 1536 * 2;  // 25,952,256 B
  u16* ATT  = (u16*)ws;                                   //  8,650,752 B
  float* Part = (float*)Xp;  // dead after gemm1; 272*66*4 = 72 KB

  prep<<<(NCH_X + NCH_WQ + NCH_WO) / 256, 256, 0, stream>>>(
      x, wq, wk, wv, wo, Xp, Wqkv, Wob);

  gemm224<<<222, 512, 0, stream>>>(Xp, Wqkv, QKV);

  attn<<<NDB + 2048, 256, 0, stream>>>(QKV, ATT, Part);
  attn_fin<<<16, 64, 0, stream>>>(Part, ATT);

  gemm160<<<208, 256, 0, stream>>>(ATT, Wob, out);
}